// Round 9
// baseline (1465.546 us; speedup 1.0000x reference)
//
#include <hip/hip_runtime.h>
#include <hip/hip_bf16.h>
#include <cstdint>

#define NB 16
#define NC 32
#define T0 16384
#define NL 30
#define SKC 256
#define TF 13315
#define TC 2432           // time-chunk (final coords)
#define XPB 5376          // ping-pong row capacity (>= TC + 2942 + tail reads)
#define ZLS ((size_t)NB*TC*NC)   // f16 elements per z layer
#define WGRP 192          // final cols per group block
#define XBC 320           // staged col capacity in group LDS (Cin max 319)
#define XBS 18            // x LDS col stride in u32 (72B; 2-way bank alias = free)
#define ZBS 20            // zbuf row stride in u32 (80B)

typedef _Float16 f16;
typedef _Float16 f16x2 __attribute__((ext_vector_type(2)));
typedef _Float16 f16x8 __attribute__((ext_vector_type(8)));
typedef float f32x4 __attribute__((ext_vector_type(4)));
typedef uint32_t u32;

#define MFMA16(a,b,c) __builtin_amdgcn_mfma_f32_16x16x32_f16(a,b,c,0,0,0)

#define SCF (-2.88539008f)   // -2*log2(e): ef = e^-2f = 2^(SCF*f)
#define SCG (-1.44269504f)   // -log2(e):   eg = e^-g  = 2^(SCG*g)
#define CLF 86.6f
#define CLG 43.3f

__device__ __forceinline__ float frcp(float x){
#if __has_builtin(__builtin_amdgcn_rcpf)
  return __builtin_amdgcn_rcpf(x);
#else
  return 1.f/x;
#endif
}
__device__ __forceinline__ float fexp2(float x){
#if __has_builtin(__builtin_amdgcn_exp2f)
  return __builtin_amdgcn_exp2f(x);
#else
  return exp2f(x);
#endif
}
__device__ __forceinline__ u32 perm_lo(u32 a, u32 b){
#if __has_builtin(__builtin_amdgcn_perm)
  return __builtin_amdgcn_perm(b, a, 0x05040100u);
#else
  return (a & 0xffffu) | (b << 16);
#endif
}
__device__ __forceinline__ u32 perm_hi(u32 a, u32 b){
#if __has_builtin(__builtin_amdgcn_perm)
  return __builtin_amdgcn_perm(b, a, 0x07060302u);
#else
  return (a >> 16) | (b & 0xffff0000u);
#endif
}
__device__ __forceinline__ u32 pk2(float x, float y){
#if __has_builtin(__builtin_amdgcn_cvt_pkrtz)
  return __builtin_bit_cast(u32, __builtin_amdgcn_cvt_pkrtz(x, y));
#else
  f16x2 r; r.x = (f16)x; r.y = (f16)y;
  return __builtin_bit_cast(u32, r);
#endif
}

// ---------------- prep: weights -> f16 fragment order / pair layouts --------
__global__ __launch_bounds__(256) void prep3(
    const float* __restrict__ sw, const float* __restrict__ e1w,
    const float* __restrict__ e2w, const float* __restrict__ fw,
    const float* __restrict__ gw, const float* __restrict__ rw,
    f16* __restrict__ wsk, f16* __restrict__ e1f, f16* __restrict__ e2f,
    u32* __restrict__ fgp, u32* __restrict__ ggp, u32* __restrict__ rwp){
  int idx = blockIdx.x*256 + threadIdx.x;
  if (idx < 30720){                    // skip weights frag: [i][mt][lane][8]
    int lane = idx & 63, mt = (idx>>6)&15, i = idx>>10;
    int m = mt*16 + (lane&15);
    int kl = (lane>>4)*8;
    const float* s = sw + ((size_t)i*SKC + m)*NC + kl;
    f16* dp = wsk + (size_t)idx*8;
    #pragma unroll
    for (int j=0;j<8;j++) dp[j] = (f16)s[j];
  } else if (idx < 38912){             // e1 frag: [ks][mt][lane][8]
    int j2 = idx - 30720;
    int lane = j2&63, mt = (j2>>6)&15, ks = j2>>10;
    int m = mt*16 + (lane&15);
    int k = ks*32 + (lane>>4)*8;
    const float* s = e1w + (size_t)m*SKC + k;
    f16* dp = e1f + (size_t)j2*8;
    #pragma unroll
    for (int j=0;j<8;j++) dp[j] = (f16)s[j];
  } else if (idx < 47104){             // e2 frag
    int j2 = idx - 38912;
    int lane = j2&63, mt = (j2>>6)&15, ks = j2>>10;
    int m = mt*16 + (lane&15);
    int k = ks*32 + (lane>>4)*8;
    const float* s = e2w + (size_t)m*SKC + k;
    f16* dp = e2f + (size_t)j2*8;
    #pragma unroll
    for (int j=0;j<8;j++) dp[j] = (f16)s[j];
  } else if (idx < 77824){             // filt pairs, exp2-scaled
    int j2 = idx - 47104;
    const float* s = fw + (size_t)j2*2;
    f16x2 p; p.x = (f16)(s[0]*SCF); p.y = (f16)(s[1]*SCF);
    fgp[j2] = __builtin_bit_cast(u32, p);
  } else if (idx < 108544){            // gate pairs, exp2-scaled
    int j2 = idx - 77824;
    const float* s = gw + (size_t)j2*2;
    f16x2 p; p.x = (f16)(s[0]*SCG); p.y = (f16)(s[1]*SCG);
    ggp[j2] = __builtin_bit_cast(u32, p);
  } else if (idx < 123904){            // res rows
    int j2 = idx - 108544;
    int i = j2 >> 9, c = (j2>>4)&31, j = j2&15;
    const float* s = rw + ((size_t)i*NC + c)*NC + 2*j;
    f16x2 p; p.x = (f16)s[0]; p.y = (f16)s[1];
    rwp[j2] = __builtin_bit_cast(u32, p);
  }
}

// ---------------- per-layer weight fragments ----------------
struct LW { f16x8 af[4]; f16x8 ag[4]; f16x8 ar[2]; };
__device__ __forceinline__ void lw_load(LW& w, const u32* __restrict__ fp,
    const u32* __restrict__ gp, const u32* __restrict__ rp, int lane){
  int m = lane & 15, q4 = (lane >> 4) * 4;
  #pragma unroll
  for (int mh = 0; mh < 2; mh++){
    #pragma unroll
    for (int kc = 0; kc < 2; kc++){
      w.af[mh*2+kc] = *(const f16x8*)&fp[(mh*16+m)*32 + kc*16 + q4];
      w.ag[mh*2+kc] = *(const f16x8*)&gp[(mh*16+m)*32 + kc*16 + q4];
    }
    w.ar[mh] = *(const f16x8*)&rp[(mh*16+m)*16 + q4];
  }
}

// ---------------- 16-col tile engine: conv->gate->res via MFMA --------------
__device__ __forceinline__ void tile_core(const LW& w,
    uint2 a0, uint2 a1, uint2 b0, uint2 b1,
    u32* zbw, int lane, uint2& xo0, uint2& xo1){
  uint4 B0u = make_uint4(perm_lo(a0.x,b0.x), perm_hi(a0.x,b0.x),
                         perm_lo(a0.y,b0.y), perm_hi(a0.y,b0.y));
  uint4 B1u = make_uint4(perm_lo(a1.x,b1.x), perm_hi(a1.x,b1.x),
                         perm_lo(a1.y,b1.y), perm_hi(a1.y,b1.y));
  f16x8 B0 = __builtin_bit_cast(f16x8, B0u);
  f16x8 B1 = __builtin_bit_cast(f16x8, B1u);
  f32x4 z4 = {0.f,0.f,0.f,0.f};
  f32x4 fa0 = MFMA16(w.af[0], B0, z4); fa0 = MFMA16(w.af[1], B1, fa0);
  f32x4 fa1 = MFMA16(w.af[2], B0, z4); fa1 = MFMA16(w.af[3], B1, fa1);
  f32x4 ga0 = MFMA16(w.ag[0], B0, z4); ga0 = MFMA16(w.ag[1], B1, ga0);
  f32x4 ga1 = MFMA16(w.ag[2], B0, z4); ga1 = MFMA16(w.ag[3], B1, ga1);
  u32 zq[4];
  #pragma unroll
  for (int mh = 0; mh < 2; mh++){
    f32x4 fv = mh ? fa1 : fa0;
    f32x4 gv = mh ? ga1 : ga0;
    float zz[4];
    #pragma unroll
    for (int r = 0; r < 4; r++){
      float fc = fminf(fmaxf(fv[r], -CLF), CLF);
      float gc = fminf(fmaxf(gv[r], -CLG), CLG);
      float ef = fexp2(fc);
      float eg = fexp2(gc);
      zz[r] = (1.f - ef) * frcp((1.f + ef) * (1.f + eg));
    }
    zq[mh*2+0] = pk2(zz[0], zz[1]);
    zq[mh*2+1] = pk2(zz[2], zz[3]);
  }
  int t = lane & 15, q = lane >> 4;
  *(uint2*)&zbw[t*ZBS + q*2]     = make_uint2(zq[0], zq[1]);
  *(uint2*)&zbw[t*ZBS + 8 + q*2] = make_uint2(zq[2], zq[3]);
  f16x8 zB = *(const f16x8*)&zbw[t*ZBS + q*4];
  f32x4 r0 = MFMA16(w.ar[0], zB, z4);
  f32x4 r1 = MFMA16(w.ar[1], zB, z4);
  f16x2 b00 = __builtin_bit_cast(f16x2, b0.x);
  f16x2 b01 = __builtin_bit_cast(f16x2, b0.y);
  f16x2 b10 = __builtin_bit_cast(f16x2, b1.x);
  f16x2 b11 = __builtin_bit_cast(f16x2, b1.y);
  xo0.x = pk2(r0[0] + (float)b00.x, r0[1] + (float)b00.y);
  xo0.y = pk2(r0[2] + (float)b01.x, r0[3] + (float)b01.y);
  xo1.x = pk2(r1[0] + (float)b10.x, r1[1] + (float)b10.y);
  xo1.y = pk2(r1[2] + (float)b11.x, r1[3] + (float)b11.y);
}

// ---------------- fused 7-layer group (d=1..64), MFMA, 192-col blocks -------
struct Trim7 { int t[7]; };

__global__ __launch_bounds__(256, 3) void group7m(
    const f16* __restrict__ xin, const float* __restrict__ y,
    const float* __restrict__ cw, const float* __restrict__ cb, int tc0,
    f16* __restrict__ xout, f16* __restrict__ zbase, int g0,
    int Lfinal, int TcAct,
    const u32* __restrict__ fgp, const u32* __restrict__ ggp,
    const u32* __restrict__ rwp, Trim7 trims){
  __shared__ u32 xb[2][XBC*XBS];    // 46,080 B
  __shared__ u32 zbuf[4][16*ZBS];   //  5,120 B  (total 51,200 -> 3 blocks/CU)
  int tid = threadIdx.x, b = blockIdx.y, o0 = blockIdx.x*WGRP;
  int lane = tid & 63, widx = tid >> 6;
  int Cf = Lfinal - o0; if (Cf > WGRP) Cf = WGRP;
  int Cin = Cf + 127;
  for (int p = tid; p < Cin; p += 256){
    u32* dst = &xb[0][p*XBS];
    if (y != nullptr){
      float yv = y[(size_t)b*T0 + tc0 + o0 + p];
      #pragma unroll
      for (int j = 0; j < 16; j++)
        dst[j] = pk2(fmaf(cw[2*j], yv, cb[2*j]), fmaf(cw[2*j+1], yv, cb[2*j+1]));
    } else {
      const uint4* src = (const uint4*)(xin + ((size_t)b*XPB + o0 + p)*NC);
      uint4 v0 = src[0], v1 = src[1], v2 = src[2], v3 = src[3];
      uint2* d2 = (uint2*)dst;
      d2[0] = make_uint2(v0.x,v0.y); d2[1] = make_uint2(v0.z,v0.w);
      d2[2] = make_uint2(v1.x,v1.y); d2[3] = make_uint2(v1.z,v1.w);
      d2[4] = make_uint2(v2.x,v2.y); d2[5] = make_uint2(v2.z,v2.w);
      d2[6] = make_uint2(v3.x,v3.y); d2[7] = make_uint2(v3.z,v3.w);
    }
  }
  __syncthreads();
  int cur = 0;
  #pragma unroll 1
  for (int li = 0; li < 7; li++){
    int d = 1 << li;
    int count = Cf + 128 - (2 << li);
    LW w;
    lw_load(w, fgp + (size_t)(g0+li)*1024, ggp + (size_t)(g0+li)*1024,
            rwp + (size_t)(g0+li)*512, lane);
    f16* zl = zbase + (size_t)(g0+li)*ZLS + (size_t)b*TC*NC;
    int trim = trims.t[li];
    int ntiles = (count + 15) >> 4;
    u32* zbw = zbuf[widx];
    for (int ti = widx; ti < ntiles; ti += 4){
      int t0 = ti*16;
      int c = t0 + (lane & 15), q = lane >> 4;
      const u32* xc = &xb[cur][c*XBS];
      const u32* xd = &xb[cur][(c+d)*XBS];
      uint2 a0 = *(const uint2*)&xc[q*2];
      uint2 a1 = *(const uint2*)&xc[8 + q*2];
      uint2 b0 = *(const uint2*)&xd[q*2];
      uint2 b1 = *(const uint2*)&xd[8 + q*2];
      uint2 xo0, xo1;
      tile_core(w, a0, a1, b0, b1, zbw, lane, xo0, xo1);
      u32* xn = &xb[cur^1][c*XBS];
      *(uint2*)&xn[q*2] = xo0;
      *(uint2*)&xn[8 + q*2] = xo1;
      int zr = lane >> 2, zc4 = (lane & 3) * 4;
      uint4 zv = *(const uint4*)&zbw[zr*ZBS + zc4];
      int p = t0 + zr;
      int lz = o0 + p - trim;
      if (p < count && lz >= 0 && lz < TcAct)
        *(uint4*)(zl + (size_t)lz*NC + zc4*2) = zv;
    }
    __syncthreads();
    cur ^= 1;
  }
  for (int p = tid; p < Cf; p += 256){
    const uint2* s2 = (const uint2*)&xb[cur][p*XBS];
    uint2 v[8];
    #pragma unroll
    for (int j=0;j<8;j++) v[j] = s2[j];
    uint4* dd = (uint4*)(xout + ((size_t)b*XPB + o0 + p)*NC);
    dd[0] = make_uint4(v[0].x,v[0].y,v[1].x,v[1].y);
    dd[1] = make_uint4(v[2].x,v[2].y,v[3].x,v[3].y);
    dd[2] = make_uint4(v[4].x,v[4].y,v[5].x,v[5].y);
    dd[3] = make_uint4(v[6].x,v[6].y,v[7].x,v[7].y);
  }
}

// -------- single dilated layer (d=128/256/512), MFMA, 2 tiles/wave ----------
__global__ __launch_bounds__(256, 3) void singlem(
    const f16* __restrict__ xin, f16* __restrict__ xout, f16* __restrict__ zl,
    const u32* __restrict__ fp, const u32* __restrict__ gp,
    const u32* __restrict__ rp, int Tout, int d, int trim, int TcAct){
  __shared__ u32 zbuf[8][16*ZBS];   // 40,960 B
  int tid = threadIdx.x, b = blockIdx.y;
  int lane = tid & 63, widx = tid >> 6;
  int t0A = (blockIdx.x*8 + widx*2) * 16;
  if (t0A >= Tout) return;
  int haveB = (t0A + 16) < Tout;
  LW w;
  lw_load(w, fp, gp, rp, lane);
  int tl = lane & 15, q = lane >> 4;
  const f16* xbase = xin + (size_t)b*XPB*NC;
  // tile A
  int cA = t0A + tl;
  const f16* xcA = xbase + (size_t)cA*NC;
  const f16* xdA = xcA + (size_t)d*NC;
  uint2 a0A = *(const uint2*)(xcA + q*4);
  uint2 a1A = *(const uint2*)(xcA + 16 + q*4);
  uint2 b0A = *(const uint2*)(xdA + q*4);
  uint2 b1A = *(const uint2*)(xdA + 16 + q*4);
  // tile B
  int cB = cA + 16;
  const f16* xcB = xbase + (size_t)cB*NC;
  const f16* xdB = xcB + (size_t)d*NC;
  uint2 a0B = *(const uint2*)(xcB + q*4);
  uint2 a1B = *(const uint2*)(xcB + 16 + q*4);
  uint2 b0B = *(const uint2*)(xdB + q*4);
  uint2 b1B = *(const uint2*)(xdB + 16 + q*4);

  uint2 xo0A, xo1A, xo0B, xo1B;
  tile_core(w, a0A, a1A, b0A, b1A, zbuf[widx*2],   lane, xo0A, xo1A);
  tile_core(w, a0B, a1B, b0B, b1B, zbuf[widx*2+1], lane, xo0B, xo1B);

  if (cA < Tout){
    f16* xoc = xout + ((size_t)b*XPB + cA)*NC;
    *(uint2*)(xoc + q*4) = xo0A;
    *(uint2*)(xoc + 16 + q*4) = xo1A;
  }
  if (haveB && cB < Tout){
    f16* xoc = xout + ((size_t)b*XPB + cB)*NC;
    *(uint2*)(xoc + q*4) = xo0B;
    *(uint2*)(xoc + 16 + q*4) = xo1B;
  }
  int zr = lane >> 2, zc4 = (lane & 3) * 4;
  {
    uint4 zv = *(const uint4*)&zbuf[widx*2][zr*ZBS + zc4];
    int p = t0A + zr, lz = p - trim;
    if (p < Tout && lz >= 0 && lz < TcAct)
      *(uint4*)(zl + ((size_t)b*TC + lz)*NC + zc4*2) = zv;
  }
  if (haveB){
    uint4 zv = *(const uint4*)&zbuf[widx*2+1][zr*ZBS + zc4];
    int p = t0A + 16 + zr, lz = p - trim;
    if (p < Tout && lz >= 0 && lz < TcAct)
      *(uint4*)(zl + ((size_t)b*TC + lz)*NC + zc4*2) = zv;
  }
}

// ------- fused skip(K=960) -> relu -> end1 -> relu -> end2, write f32 -------
// 3-layer groups, z double-buffered in LDS, ONE barrier per group (10 total).
__global__ __launch_bounds__(256, 3) void skipend(
    const f16* __restrict__ zbase,
    const f16* __restrict__ wsk, const f16* __restrict__ e1f,
    const float* __restrict__ e1b, const f16* __restrict__ e2f,
    const float* __restrict__ e2b, float* __restrict__ out,
    int tc0, int TcAct){
  __shared__ u32 smem[64*132];        // 33,792 B; zls[2][3][1280] aliases front
  int tid = threadIdx.x, b = blockIdx.y, t0 = blockIdx.x*64;
  int w = tid>>6, lane = tid&63;
  int tl = lane & 15;
  int q  = lane >> 4;
  const uint4* wsk4 = (const uint4*)wsk;
  const uint4* e1f4 = (const uint4*)e1f;
  const uint4* e2f4 = (const uint4*)e2f;

  const f16* zcol = zbase + ((size_t)b*TC + t0 + (tid>>2))*NC + (tid&3)*8;
  int zw = (tid>>2)*20 + (tid&3)*4;

  f32x4 acc[4][4];
  #pragma unroll
  for (int j=0;j<4;j++)
    #pragma unroll
    for (int tt=0;tt<4;tt++) acc[j][tt] = f32x4{0.f,0.f,0.f,0.f};

  uint4 zst[3];
  // prologue: group 0 -> buf0
  #pragma unroll
  for (int k=0;k<3;k++) zst[k] = *(const uint4*)(zcol + (size_t)k*ZLS);
  #pragma unroll
  for (int k=0;k<3;k++) *(uint4*)&smem[(size_t)k*1280 + zw] = zst[k];

  #pragma unroll 1
  for (int g = 0; g < 10; g++){
    __syncthreads();                       // buf[g&1] ready
    int lbase = g*3;
    u32* bufr = smem + (size_t)(g&1)*3840;
    // prefetch next group's z (issue early; consumed after MFMA)
    if (g < 9){
      #pragma unroll
      for (int k=0;k<3;k++)
        zst[k] = *(const uint4*)(zcol + (size_t)(lbase+3+k)*ZLS);
    }
    #pragma unroll
    for (int k=0;k<3;k++){
      uint4 aw[4];
      #pragma unroll
      for (int j=0;j<4;j++)
        aw[j] = wsk4[(size_t)(lbase+k)*1024 + (w*4+j)*64 + lane];
      f16x8 zb[4];
      #pragma unroll
      for (int tt=0;tt<4;tt++)
        zb[tt] = *(const f16x8*)&bufr[(size_t)k*1280 + (tt*16+tl)*20 + q*4];
      #pragma unroll
      for (int j=0;j<4;j++){
        f16x8 a = __builtin_bit_cast(f16x8, aw[j]);
        #pragma unroll
        for (int tt=0;tt<4;tt++)
          acc[j][tt] = MFMA16(a, zb[tt], acc[j][tt]);
      }
    }
    if (g < 9){
      u32* bufw = smem + (size_t)((g+1)&1)*3840;
      #pragma unroll
      for (int k=0;k<3;k++) *(uint4*)&bufw[(size_t)k*1280 + zw] = zst[k];
    }
  }
  __syncthreads();
  // phase2: relu(skip) -> sA [t][264 f16]
  int rq = q*4;
  #pragma unroll
  for (int j=0;j<4;j++){
    int c0 = (w*4+j)*16 + rq;
    #pragma unroll
    for (int tt=0;tt<4;tt++){
      int t = tt*16 + tl;
      u32 p0 = pk2(fmaxf(acc[j][tt][0],0.f), fmaxf(acc[j][tt][1],0.f));
      u32 p1 = pk2(fmaxf(acc[j][tt][2],0.f), fmaxf(acc[j][tt][3],0.f));
      *(uint2*)&smem[t*132 + (c0>>1)] = make_uint2(p0, p1);
    }
  }
  __syncthreads();
  // phase3: end1
  #pragma unroll
  for (int j=0;j<4;j++)
    #pragma unroll
    for (int tt=0;tt<4;tt++) acc[j][tt] = f32x4{0.f,0.f,0.f,0.f};
  #pragma unroll
  for (int ks=0;ks<8;ks++){
    f16x8 zb[4];
    #pragma unroll
    for (int tt=0;tt<4;tt++)
      zb[tt] = *(const f16x8*)&smem[(tt*16+tl)*132 + ks*16 + q*4];
    #pragma unroll
    for (int j=0;j<4;j++){
      f16x8 a = __builtin_bit_cast(f16x8, e1f4[(size_t)(ks*16 + w*4+j)*64 + lane]);
      #pragma unroll
      for (int tt=0;tt<4;tt++)
        acc[j][tt] = MFMA16(a, zb[tt], acc[j][tt]);
    }
  }
  __syncthreads();     // all sA reads done; safe to overwrite with sB
  #pragma unroll
  for (int j=0;j<4;j++){
    int c0 = (w*4+j)*16 + rq;
    float4 bv = *(const float4*)&e1b[c0];
    #pragma unroll
    for (int tt=0;tt<4;tt++){
      int t = tt*16 + tl;
      u32 p0 = pk2(fmaxf(acc[j][tt][0]+bv.x,0.f), fmaxf(acc[j][tt][1]+bv.y,0.f));
      u32 p1 = pk2(fmaxf(acc[j][tt][2]+bv.z,0.f), fmaxf(acc[j][tt][3]+bv.w,0.f));
      *(uint2*)&smem[t*132 + (c0>>1)] = make_uint2(p0, p1);
    }
  }
  __syncthreads();
  // phase4: end2 + final write
  #pragma unroll
  for (int j=0;j<4;j++)
    #pragma unroll
    for (int tt=0;tt<4;tt++) acc[j][tt] = f32x4{0.f,0.f,0.f,0.f};
  #pragma unroll
  for (int ks=0;ks<8;ks++){
    f16x8 zb[4];
    #pragma unroll
    for (int tt=0;tt<4;tt++)
      zb[tt] = *(const f16x8*)&smem[(tt*16+tl)*132 + ks*16 + q*4];
    #pragma unroll
    for (int j=0;j<4;j++){
      f16x8 a = __builtin_bit_cast(f16x8, e2f4[(size_t)(ks*16 + w*4+j)*64 + lane]);
      #pragma unroll
      for (int tt=0;tt<4;tt++)
        acc[j][tt] = MFMA16(a, zb[tt], acc[j][tt]);
    }
  }
  #pragma unroll
  for (int j=0;j<4;j++){
    int c0 = (w*4+j)*16 + rq;
    float4 bv = *(const float4*)&e2b[c0];
    #pragma unroll
    for (int tt=0;tt<4;tt++){
      int t = tt*16 + tl;
      if (t0 + t < TcAct){
        float* op = out + ((size_t)b*SKC + c0)*TF + tc0 + t0 + t;
        op[0*TF] = acc[j][tt][0] + bv.x;
        op[1*TF] = acc[j][tt][1] + bv.y;
        op[2*TF] = acc[j][tt][2] + bv.z;
        op[3*TF] = acc[j][tt][3] + bv.w;
      }
    }
  }
}

extern "C" void kernel_launch(void* const* d_in, const int* in_sizes, int n_in,
                              void* d_out, int out_size, void* d_ws, size_t ws_size,
                              hipStream_t stream) {
  (void)in_sizes; (void)n_in; (void)out_size; (void)ws_size;
  const float* y   = (const float*)d_in[0];
  const float* cw  = (const float*)d_in[1];
  const float* cb  = (const float*)d_in[2];
  const float* fw  = (const float*)d_in[3];
  const float* gw  = (const float*)d_in[4];
  const float* rw  = (const float*)d_in[5];
  const float* sw  = (const float*)d_in[6];
  const float* e1w = (const float*)d_in[7];
  const float* e1b = (const float*)d_in[8];
  const float* e2w = (const float*)d_in[9];
  const float* e2b = (const float*)d_in[10];
  float* out = (float*)d_out;
  char* ws = (char*)d_ws;

  // ws layout, total 86,781,952 B (proven ws >= 89,403,392)
  f16* wsk  = (f16*)(ws);                       //   491,520
  f16* e1f  = (f16*)(ws +   491520);            //   131,072
  f16* e2f  = (f16*)(ws +   622592);            //   131,072
  u32* fgp  = (u32*)(ws +  753664);             //   122,880
  u32* ggp  = (u32*)(ws +  876544);             //   122,880
  u32* rwp  = (u32*)(ws +  999424);             //    61,440
  f16* xpA  = (f16*)(ws + 1060864);             // 5,505,024
  f16* xpB  = (f16*)(ws + 6565888);             // 5,505,024
  f16* zstack = (f16*)(ws + 12070912);          // 74,711,040

  int S[NL+1]; S[NL] = 0;
  for (int i = NL-1; i >= 0; i--) S[i] = S[i+1] + (1 << (i % 10));

  prep3<<<dim3(484), 256, 0, stream>>>(sw, e1w, e2w, fw, gw, rw,
                                       wsk, e1f, e2f, fgp, ggp, rwp);

  f16* bufs[2] = {xpA, xpB};
  for (int tc0 = 0; tc0 < TF; tc0 += TC){
    int TcAct = TF - tc0; if (TcAct > TC) TcAct = TC;
    int cur = 0;
    for (int s = 0; s < 3; s++){
      int g0 = s*10;
      Trim7 tr;
      for (int li = 0; li < 7; li++) tr.t[li] = S[g0+li+1];
      int Lfinal = TcAct + S[g0+7];
      const f16* gin = (s == 0) ? (const f16*)nullptr : bufs[cur];
      const float* yArg = (s == 0) ? y : (const float*)nullptr;
      int nxt = (s == 0) ? 0 : (cur ^ 1);
      group7m<<<dim3((Lfinal + WGRP-1)/WGRP, NB), 256, 0, stream>>>(
          gin, yArg, cw, cb, tc0, bufs[nxt], zstack, g0, Lfinal, TcAct,
          fgp, ggp, rwp, tr);
      cur = nxt;
      for (int i = g0+7; i <= g0+9; i++){
        int d = 1 << (i % 10);
        int Tout = TcAct + S[i+1];
        singlem<<<dim3((Tout + 127)/128, NB), 256, 0, stream>>>(
            bufs[cur], bufs[cur^1], zstack + (size_t)i*ZLS,
            fgp + (size_t)i*1024, ggp + (size_t)i*1024, rwp + (size_t)i*512,
            Tout, d, S[i+1], TcAct);
        cur ^= 1;
      }
    }
    skipend<<<dim3((TcAct + 63)/64, NB), 256, 0, stream>>>(
        zstack, wsk, e1f, e1b, e2f, e2b, out, tc0, TcAct);
  }
}

// Round 10
// 1362.756 us; speedup vs baseline: 1.0754x; 1.0754x over previous
//
#include <hip/hip_runtime.h>
#include <hip/hip_bf16.h>
#include <cstdint>

#define NB 16
#define NC 32
#define T0 16384
#define NL 30
#define SKC 256
#define TF 13315
#define TC 2432           // time-chunk (final coords); 38*64
#define XPB 5376          // ping-pong row capacity (>= TC + 2942 + tail reads)
#define ZLS ((size_t)NB*TC*NC)   // f16 elements per z layer
#define ZSTEP (ZLS/8)            // uint4 per z layer
#define WGRP 192          // final cols per group block
#define XBC 320           // staged col capacity in group LDS (Cin max 319)
#define XBS 18            // x LDS col stride in u32 (72B; max 2-way alias = free)
#define ZBS 20            // zbuf row stride in u32 (80B)

typedef _Float16 f16;
typedef _Float16 f16x2 __attribute__((ext_vector_type(2)));
typedef _Float16 f16x8 __attribute__((ext_vector_type(8)));
typedef float f32x4 __attribute__((ext_vector_type(4)));
typedef uint32_t u32;

#define MFMA16(a,b,c) __builtin_amdgcn_mfma_f32_16x16x32_f16(a,b,c,0,0,0)

#define SCF (-2.88539008f)   // -2*log2(e): ef = e^-2f = 2^(SCF*f)
#define SCG (-1.44269504f)   // -log2(e):   eg = e^-g  = 2^(SCG*g)
#define CLF 86.6f
#define CLG 43.3f

__device__ __forceinline__ float frcp(float x){
#if __has_builtin(__builtin_amdgcn_rcpf)
  return __builtin_amdgcn_rcpf(x);
#else
  return 1.f/x;
#endif
}
__device__ __forceinline__ float fexp2(float x){
#if __has_builtin(__builtin_amdgcn_exp2f)
  return __builtin_amdgcn_exp2f(x);
#else
  return exp2f(x);
#endif
}
__device__ __forceinline__ u32 perm_lo(u32 a, u32 b){
#if __has_builtin(__builtin_amdgcn_perm)
  return __builtin_amdgcn_perm(b, a, 0x05040100u);
#else
  return (a & 0xffffu) | (b << 16);
#endif
}
__device__ __forceinline__ u32 perm_hi(u32 a, u32 b){
#if __has_builtin(__builtin_amdgcn_perm)
  return __builtin_amdgcn_perm(b, a, 0x07060302u);
#else
  return (a >> 16) | (b & 0xffff0000u);
#endif
}
__device__ __forceinline__ u32 pk2(float x, float y){
#if __has_builtin(__builtin_amdgcn_cvt_pkrtz)
  return __builtin_bit_cast(u32, __builtin_amdgcn_cvt_pkrtz(x, y));
#else
  f16x2 r; r.x = (f16)x; r.y = (f16)y;
  return __builtin_bit_cast(u32, r);
#endif
}
// z-stack fragment layout: per (b, 64t-block): [tt=(t>>4)&3][lane=q*16+(t&15)][8 ch]
// Producer store offset (within layer+batch base), q = channel-octet index:
__device__ __forceinline__ size_t zfrag_off(int lz, int q){
  return (size_t)(lz & ~63)*NC + (size_t)(((lz>>4)&3)*512 + (q*16 + (lz&15))*8);
}

// ---------------- prep: weights -> f16 fragment order / pair layouts --------
__global__ __launch_bounds__(256) void prep3(
    const float* __restrict__ sw, const float* __restrict__ e1w,
    const float* __restrict__ e2w, const float* __restrict__ fw,
    const float* __restrict__ gw, const float* __restrict__ rw,
    f16* __restrict__ wsk, f16* __restrict__ e1f, f16* __restrict__ e2f,
    u32* __restrict__ fgp, u32* __restrict__ ggp, u32* __restrict__ rwp){
  int idx = blockIdx.x*256 + threadIdx.x;
  if (idx < 30720){                    // skip weights frag: [i][mt][lane][8]
    int lane = idx & 63, mt = (idx>>6)&15, i = idx>>10;
    int m = mt*16 + (lane&15);
    int kl = (lane>>4)*8;
    const float* s = sw + ((size_t)i*SKC + m)*NC + kl;
    f16* dp = wsk + (size_t)idx*8;
    #pragma unroll
    for (int j=0;j<8;j++) dp[j] = (f16)s[j];
  } else if (idx < 38912){             // e1 frag: [ks][mt][lane][8]
    int j2 = idx - 30720;
    int lane = j2&63, mt = (j2>>6)&15, ks = j2>>10;
    int m = mt*16 + (lane&15);
    int k = ks*32 + (lane>>4)*8;
    const float* s = e1w + (size_t)m*SKC + k;
    f16* dp = e1f + (size_t)j2*8;
    #pragma unroll
    for (int j=0;j<8;j++) dp[j] = (f16)s[j];
  } else if (idx < 47104){             // e2 frag
    int j2 = idx - 38912;
    int lane = j2&63, mt = (j2>>6)&15, ks = j2>>10;
    int m = mt*16 + (lane&15);
    int k = ks*32 + (lane>>4)*8;
    const float* s = e2w + (size_t)m*SKC + k;
    f16* dp = e2f + (size_t)j2*8;
    #pragma unroll
    for (int j=0;j<8;j++) dp[j] = (f16)s[j];
  } else if (idx < 77824){             // filt pairs, exp2-scaled
    int j2 = idx - 47104;
    const float* s = fw + (size_t)j2*2;
    f16x2 p; p.x = (f16)(s[0]*SCF); p.y = (f16)(s[1]*SCF);
    fgp[j2] = __builtin_bit_cast(u32, p);
  } else if (idx < 108544){            // gate pairs, exp2-scaled
    int j2 = idx - 77824;
    const float* s = gw + (size_t)j2*2;
    f16x2 p; p.x = (f16)(s[0]*SCG); p.y = (f16)(s[1]*SCG);
    ggp[j2] = __builtin_bit_cast(u32, p);
  } else if (idx < 123904){            // res rows
    int j2 = idx - 108544;
    int i = j2 >> 9, c = (j2>>4)&31, j = j2&15;
    const float* s = rw + ((size_t)i*NC + c)*NC + 2*j;
    f16x2 p; p.x = (f16)s[0]; p.y = (f16)s[1];
    rwp[j2] = __builtin_bit_cast(u32, p);
  }
}

// ---------------- per-layer weight fragments ----------------
struct LW { f16x8 af[4]; f16x8 ag[4]; f16x8 ar[2]; };
__device__ __forceinline__ void lw_load(LW& w, const u32* __restrict__ fp,
    const u32* __restrict__ gp, const u32* __restrict__ rp, int lane){
  int m = lane & 15, q4 = (lane >> 4) * 4;
  #pragma unroll
  for (int mh = 0; mh < 2; mh++){
    #pragma unroll
    for (int kc = 0; kc < 2; kc++){
      w.af[mh*2+kc] = *(const f16x8*)&fp[(mh*16+m)*32 + kc*16 + q4];
      w.ag[mh*2+kc] = *(const f16x8*)&gp[(mh*16+m)*32 + kc*16 + q4];
    }
    w.ar[mh] = *(const f16x8*)&rp[(mh*16+m)*16 + q4];
  }
}

// ---------------- 16-col tile engine: conv->gate->res via MFMA --------------
__device__ __forceinline__ void tile_core(const LW& w,
    uint2 a0, uint2 a1, uint2 b0, uint2 b1,
    u32* zbw, int lane, uint2& xo0, uint2& xo1){
  uint4 B0u = make_uint4(perm_lo(a0.x,b0.x), perm_hi(a0.x,b0.x),
                         perm_lo(a0.y,b0.y), perm_hi(a0.y,b0.y));
  uint4 B1u = make_uint4(perm_lo(a1.x,b1.x), perm_hi(a1.x,b1.x),
                         perm_lo(a1.y,b1.y), perm_hi(a1.y,b1.y));
  f16x8 B0 = __builtin_bit_cast(f16x8, B0u);
  f16x8 B1 = __builtin_bit_cast(f16x8, B1u);
  f32x4 z4 = {0.f,0.f,0.f,0.f};
  f32x4 fa0 = MFMA16(w.af[0], B0, z4); fa0 = MFMA16(w.af[1], B1, fa0);
  f32x4 fa1 = MFMA16(w.af[2], B0, z4); fa1 = MFMA16(w.af[3], B1, fa1);
  f32x4 ga0 = MFMA16(w.ag[0], B0, z4); ga0 = MFMA16(w.ag[1], B1, ga0);
  f32x4 ga1 = MFMA16(w.ag[2], B0, z4); ga1 = MFMA16(w.ag[3], B1, ga1);
  u32 zq[4];
  #pragma unroll
  for (int mh = 0; mh < 2; mh++){
    f32x4 fv = mh ? fa1 : fa0;
    f32x4 gv = mh ? ga1 : ga0;
    float zz[4];
    #pragma unroll
    for (int r = 0; r < 4; r++){
      float fc = fminf(fmaxf(fv[r], -CLF), CLF);
      float gc = fminf(fmaxf(gv[r], -CLG), CLG);
      float ef = fexp2(fc);
      float eg = fexp2(gc);
      zz[r] = (1.f - ef) * frcp((1.f + ef) * (1.f + eg));
    }
    zq[mh*2+0] = pk2(zz[0], zz[1]);
    zq[mh*2+1] = pk2(zz[2], zz[3]);
  }
  int t = lane & 15, q = lane >> 4;
  *(uint2*)&zbw[t*ZBS + q*2]     = make_uint2(zq[0], zq[1]);
  *(uint2*)&zbw[t*ZBS + 8 + q*2] = make_uint2(zq[2], zq[3]);
  f16x8 zB = *(const f16x8*)&zbw[t*ZBS + q*4];
  f32x4 r0 = MFMA16(w.ar[0], zB, z4);
  f32x4 r1 = MFMA16(w.ar[1], zB, z4);
  f16x2 b00 = __builtin_bit_cast(f16x2, b0.x);
  f16x2 b01 = __builtin_bit_cast(f16x2, b0.y);
  f16x2 b10 = __builtin_bit_cast(f16x2, b1.x);
  f16x2 b11 = __builtin_bit_cast(f16x2, b1.y);
  xo0.x = pk2(r0[0] + (float)b00.x, r0[1] + (float)b00.y);
  xo0.y = pk2(r0[2] + (float)b01.x, r0[3] + (float)b01.y);
  xo1.x = pk2(r1[0] + (float)b10.x, r1[1] + (float)b10.y);
  xo1.y = pk2(r1[2] + (float)b11.x, r1[3] + (float)b11.y);
}

// ---------------- fused 7-layer group (d=1..64), MFMA, 192-col blocks -------
struct Trim7 { int t[7]; };

__global__ __launch_bounds__(256, 3) void group7m(
    const f16* __restrict__ xin, const float* __restrict__ y,
    const float* __restrict__ cw, const float* __restrict__ cb, int tc0,
    f16* __restrict__ xout, f16* __restrict__ zbase, int g0,
    int Lfinal, int TcAct,
    const u32* __restrict__ fgp, const u32* __restrict__ ggp,
    const u32* __restrict__ rwp, Trim7 trims){
  __shared__ u32 xb[2][XBC*XBS];    // 46,080 B
  __shared__ u32 zbuf[4][16*ZBS];   //  5,120 B  (total 51,200 -> 3 blocks/CU)
  int tid = threadIdx.x, b = blockIdx.y, o0 = blockIdx.x*WGRP;
  int lane = tid & 63, widx = tid >> 6;
  int Cf = Lfinal - o0; if (Cf > WGRP) Cf = WGRP;
  int Cin = Cf + 127;
  for (int p = tid; p < Cin; p += 256){
    u32* dst = &xb[0][p*XBS];
    if (y != nullptr){
      float yv = y[(size_t)b*T0 + tc0 + o0 + p];
      #pragma unroll
      for (int j = 0; j < 16; j++)
        dst[j] = pk2(fmaf(cw[2*j], yv, cb[2*j]), fmaf(cw[2*j+1], yv, cb[2*j+1]));
    } else {
      const uint4* src = (const uint4*)(xin + ((size_t)b*XPB + o0 + p)*NC);
      uint4 v0 = src[0], v1 = src[1], v2 = src[2], v3 = src[3];
      uint2* d2 = (uint2*)dst;
      d2[0] = make_uint2(v0.x,v0.y); d2[1] = make_uint2(v0.z,v0.w);
      d2[2] = make_uint2(v1.x,v1.y); d2[3] = make_uint2(v1.z,v1.w);
      d2[4] = make_uint2(v2.x,v2.y); d2[5] = make_uint2(v2.z,v2.w);
      d2[6] = make_uint2(v3.x,v3.y); d2[7] = make_uint2(v3.z,v3.w);
    }
  }
  __syncthreads();
  int cur = 0;
  #pragma unroll 1
  for (int li = 0; li < 7; li++){
    int d = 1 << li;
    int count = Cf + 128 - (2 << li);
    LW w;
    lw_load(w, fgp + (size_t)(g0+li)*1024, ggp + (size_t)(g0+li)*1024,
            rwp + (size_t)(g0+li)*512, lane);
    f16* zl = zbase + (size_t)(g0+li)*ZLS + (size_t)b*TC*NC;
    int trim = trims.t[li];
    int ntiles = (count + 15) >> 4;
    u32* zbw = zbuf[widx];
    for (int ti = widx; ti < ntiles; ti += 4){
      int t0 = ti*16;
      int c = t0 + (lane & 15), q = lane >> 4;
      const u32* xc = &xb[cur][c*XBS];
      const u32* xd = &xb[cur][(c+d)*XBS];
      uint2 a0 = *(const uint2*)&xc[q*2];
      uint2 a1 = *(const uint2*)&xc[8 + q*2];
      uint2 b0 = *(const uint2*)&xd[q*2];
      uint2 b1 = *(const uint2*)&xd[8 + q*2];
      uint2 xo0, xo1;
      tile_core(w, a0, a1, b0, b1, zbw, lane, xo0, xo1);
      u32* xn = &xb[cur^1][c*XBS];
      *(uint2*)&xn[q*2] = xo0;
      *(uint2*)&xn[8 + q*2] = xo1;
      int zr = lane >> 2, zc4 = (lane & 3) * 4;
      uint4 zv = *(const uint4*)&zbw[zr*ZBS + zc4];
      int p = t0 + zr;
      int lz = o0 + p - trim;
      if (p < count && lz >= 0 && lz < TcAct)
        *(uint4*)(zl + zfrag_off(lz, zc4>>2)) = zv;
    }
    __syncthreads();
    cur ^= 1;
  }
  for (int p = tid; p < Cf; p += 256){
    const uint2* s2 = (const uint2*)&xb[cur][p*XBS];
    uint2 v[8];
    #pragma unroll
    for (int j=0;j<8;j++) v[j] = s2[j];
    uint4* dd = (uint4*)(xout + ((size_t)b*XPB + o0 + p)*NC);
    dd[0] = make_uint4(v[0].x,v[0].y,v[1].x,v[1].y);
    dd[1] = make_uint4(v[2].x,v[2].y,v[3].x,v[3].y);
    dd[2] = make_uint4(v[4].x,v[4].y,v[5].x,v[5].y);
    dd[3] = make_uint4(v[6].x,v[6].y,v[7].x,v[7].y);
  }
}

// -------- single dilated layer (d=128/256/512), MFMA, 2 tiles/wave ----------
__global__ __launch_bounds__(256, 3) void singlem(
    const f16* __restrict__ xin, f16* __restrict__ xout, f16* __restrict__ zl,
    const u32* __restrict__ fp, const u32* __restrict__ gp,
    const u32* __restrict__ rp, int Tout, int d, int trim, int TcAct){
  __shared__ u32 zbuf[8][16*ZBS];   // 40,960 B
  int tid = threadIdx.x, b = blockIdx.y;
  int lane = tid & 63, widx = tid >> 6;
  int t0A = (blockIdx.x*8 + widx*2) * 16;
  if (t0A >= Tout) return;
  int haveB = (t0A + 16) < Tout;
  LW w;
  lw_load(w, fp, gp, rp, lane);
  int tl = lane & 15, q = lane >> 4;
  const f16* xbase = xin + (size_t)b*XPB*NC;
  int cA = t0A + tl;
  const f16* xcA = xbase + (size_t)cA*NC;
  const f16* xdA = xcA + (size_t)d*NC;
  uint2 a0A = *(const uint2*)(xcA + q*4);
  uint2 a1A = *(const uint2*)(xcA + 16 + q*4);
  uint2 b0A = *(const uint2*)(xdA + q*4);
  uint2 b1A = *(const uint2*)(xdA + 16 + q*4);
  int cB = cA + 16;
  const f16* xcB = xbase + (size_t)cB*NC;
  const f16* xdB = xcB + (size_t)d*NC;
  uint2 a0B = *(const uint2*)(xcB + q*4);
  uint2 a1B = *(const uint2*)(xcB + 16 + q*4);
  uint2 b0B = *(const uint2*)(xdB + q*4);
  uint2 b1B = *(const uint2*)(xdB + 16 + q*4);

  uint2 xo0A, xo1A, xo0B, xo1B;
  tile_core(w, a0A, a1A, b0A, b1A, zbuf[widx*2],   lane, xo0A, xo1A);
  tile_core(w, a0B, a1B, b0B, b1B, zbuf[widx*2+1], lane, xo0B, xo1B);

  if (cA < Tout){
    f16* xoc = xout + ((size_t)b*XPB + cA)*NC;
    *(uint2*)(xoc + q*4) = xo0A;
    *(uint2*)(xoc + 16 + q*4) = xo1A;
  }
  if (haveB && cB < Tout){
    f16* xoc = xout + ((size_t)b*XPB + cB)*NC;
    *(uint2*)(xoc + q*4) = xo0B;
    *(uint2*)(xoc + 16 + q*4) = xo1B;
  }
  f16* zlb = zl + (size_t)b*TC*NC;
  int zr = lane >> 2, zc4 = (lane & 3) * 4;
  {
    uint4 zv = *(const uint4*)&zbuf[widx*2][zr*ZBS + zc4];
    int p = t0A + zr, lz = p - trim;
    if (p < Tout && lz >= 0 && lz < TcAct)
      *(uint4*)(zlb + zfrag_off(lz, zc4>>2)) = zv;
  }
  if (haveB){
    uint4 zv = *(const uint4*)&zbuf[widx*2+1][zr*ZBS + zc4];
    int p = t0A + 16 + zr, lz = p - trim;
    if (p < Tout && lz >= 0 && lz < TcAct)
      *(uint4*)(zlb + zfrag_off(lz, zc4>>2)) = zv;
  }
}

// ------- fused skip(K=960) -> relu -> end1 -> relu -> end2, write f32 -------
// z-stack is in B-frag layout: main loop reads frags DIRECTLY from global
// (coalesced dwordx4), depth-2 register pipeline, ZERO barriers / LDS.
__global__ __launch_bounds__(256, 3) void skipend(
    const f16* __restrict__ zbase,
    const f16* __restrict__ wsk, const f16* __restrict__ e1f,
    const float* __restrict__ e1b, const f16* __restrict__ e2f,
    const float* __restrict__ e2b, float* __restrict__ out,
    int tc0, int TcAct){
  __shared__ u32 smem[64*132];        // 33,792 B (epilogue only)
  int tid = threadIdx.x, b = blockIdx.y, t0 = blockIdx.x*64;
  int w = tid>>6, lane = tid&63;
  int tl = lane & 15;
  int q  = lane >> 4;
  const uint4* wsk4 = (const uint4*)wsk;
  const uint4* e1f4 = (const uint4*)e1f;
  const uint4* e2f4 = (const uint4*)e2f;
  const uint4* zp = (const uint4*)(zbase + ((size_t)b*TC + t0)*NC) + lane;

  f32x4 acc[4][4];
  #pragma unroll
  for (int j=0;j<4;j++)
    #pragma unroll
    for (int tt=0;tt<4;tt++) acc[j][tt] = f32x4{0.f,0.f,0.f,0.f};

  uint4 zA[4], aA[4], zB[4], aB[4];
  #pragma unroll
  for (int tt=0;tt<4;tt++) zA[tt] = zp[tt*64];
  #pragma unroll
  for (int j=0;j<4;j++) aA[j] = wsk4[(size_t)(w*4+j)*64 + lane];

  #pragma unroll 1
  for (int l = 0; l < NL; l += 2){
    #pragma unroll
    for (int tt=0;tt<4;tt++) zB[tt] = zp[(size_t)(l+1)*ZSTEP + tt*64];
    #pragma unroll
    for (int j=0;j<4;j++)
      aB[j] = wsk4[(size_t)(l+1)*1024 + (w*4+j)*64 + lane];
    #pragma unroll
    for (int j=0;j<4;j++){
      f16x8 a = __builtin_bit_cast(f16x8, aA[j]);
      #pragma unroll
      for (int tt=0;tt<4;tt++)
        acc[j][tt] = MFMA16(a, __builtin_bit_cast(f16x8, zA[tt]), acc[j][tt]);
    }
    if (l+2 < NL){
      #pragma unroll
      for (int tt=0;tt<4;tt++) zA[tt] = zp[(size_t)(l+2)*ZSTEP + tt*64];
      #pragma unroll
      for (int j=0;j<4;j++)
        aA[j] = wsk4[(size_t)(l+2)*1024 + (w*4+j)*64 + lane];
    }
    #pragma unroll
    for (int j=0;j<4;j++){
      f16x8 a = __builtin_bit_cast(f16x8, aB[j]);
      #pragma unroll
      for (int tt=0;tt<4;tt++)
        acc[j][tt] = MFMA16(a, __builtin_bit_cast(f16x8, zB[tt]), acc[j][tt]);
    }
  }
  // phase2: relu(skip) -> sA [t][264 f16]
  int rq = q*4;
  #pragma unroll
  for (int j=0;j<4;j++){
    int c0 = (w*4+j)*16 + rq;
    #pragma unroll
    for (int tt=0;tt<4;tt++){
      int t = tt*16 + tl;
      u32 p0 = pk2(fmaxf(acc[j][tt][0],0.f), fmaxf(acc[j][tt][1],0.f));
      u32 p1 = pk2(fmaxf(acc[j][tt][2],0.f), fmaxf(acc[j][tt][3],0.f));
      *(uint2*)&smem[t*132 + (c0>>1)] = make_uint2(p0, p1);
    }
  }
  __syncthreads();
  // phase3: end1
  #pragma unroll
  for (int j=0;j<4;j++)
    #pragma unroll
    for (int tt=0;tt<4;tt++) acc[j][tt] = f32x4{0.f,0.f,0.f,0.f};
  #pragma unroll
  for (int ks=0;ks<8;ks++){
    f16x8 zb[4];
    #pragma unroll
    for (int tt=0;tt<4;tt++)
      zb[tt] = *(const f16x8*)&smem[(tt*16+tl)*132 + ks*16 + q*4];
    #pragma unroll
    for (int j=0;j<4;j++){
      f16x8 a = __builtin_bit_cast(f16x8, e1f4[(size_t)(ks*16 + w*4+j)*64 + lane]);
      #pragma unroll
      for (int tt=0;tt<4;tt++)
        acc[j][tt] = MFMA16(a, zb[tt], acc[j][tt]);
    }
  }
  __syncthreads();     // all sA reads done; safe to overwrite with sB
  #pragma unroll
  for (int j=0;j<4;j++){
    int c0 = (w*4+j)*16 + rq;
    float4 bv = *(const float4*)&e1b[c0];
    #pragma unroll
    for (int tt=0;tt<4;tt++){
      int t = tt*16 + tl;
      u32 p0 = pk2(fmaxf(acc[j][tt][0]+bv.x,0.f), fmaxf(acc[j][tt][1]+bv.y,0.f));
      u32 p1 = pk2(fmaxf(acc[j][tt][2]+bv.z,0.f), fmaxf(acc[j][tt][3]+bv.w,0.f));
      *(uint2*)&smem[t*132 + (c0>>1)] = make_uint2(p0, p1);
    }
  }
  __syncthreads();
  // phase4: end2 + final write
  #pragma unroll
  for (int j=0;j<4;j++)
    #pragma unroll
    for (int tt=0;tt<4;tt++) acc[j][tt] = f32x4{0.f,0.f,0.f,0.f};
  #pragma unroll
  for (int ks=0;ks<8;ks++){
    f16x8 zb[4];
    #pragma unroll
    for (int tt=0;tt<4;tt++)
      zb[tt] = *(const f16x8*)&smem[(tt*16+tl)*132 + ks*16 + q*4];
    #pragma unroll
    for (int j=0;j<4;j++){
      f16x8 a = __builtin_bit_cast(f16x8, e2f4[(size_t)(ks*16 + w*4+j)*64 + lane]);
      #pragma unroll
      for (int tt=0;tt<4;tt++)
        acc[j][tt] = MFMA16(a, zb[tt], acc[j][tt]);
    }
  }
  #pragma unroll
  for (int j=0;j<4;j++){
    int c0 = (w*4+j)*16 + rq;
    float4 bv = *(const float4*)&e2b[c0];
    #pragma unroll
    for (int tt=0;tt<4;tt++){
      int t = tt*16 + tl;
      if (t0 + t < TcAct){
        float* op = out + ((size_t)b*SKC + c0)*TF + tc0 + t0 + t;
        op[0*TF] = acc[j][tt][0] + bv.x;
        op[1*TF] = acc[j][tt][1] + bv.y;
        op[2*TF] = acc[j][tt][2] + bv.z;
        op[3*TF] = acc[j][tt][3] + bv.w;
      }
    }
  }
}

extern "C" void kernel_launch(void* const* d_in, const int* in_sizes, int n_in,
                              void* d_out, int out_size, void* d_ws, size_t ws_size,
                              hipStream_t stream) {
  (void)in_sizes; (void)n_in; (void)out_size; (void)ws_size;
  const float* y   = (const float*)d_in[0];
  const float* cw  = (const float*)d_in[1];
  const float* cb  = (const float*)d_in[2];
  const float* fw  = (const float*)d_in[3];
  const float* gw  = (const float*)d_in[4];
  const float* rw  = (const float*)d_in[5];
  const float* sw  = (const float*)d_in[6];
  const float* e1w = (const float*)d_in[7];
  const float* e1b = (const float*)d_in[8];
  const float* e2w = (const float*)d_in[9];
  const float* e2b = (const float*)d_in[10];
  float* out = (float*)d_out;
  char* ws = (char*)d_ws;

  // ws layout, total 86,781,952 B (proven ws >= 89,403,392)
  f16* wsk  = (f16*)(ws);                       //   491,520
  f16* e1f  = (f16*)(ws +   491520);            //   131,072
  f16* e2f  = (f16*)(ws +   622592);            //   131,072
  u32* fgp  = (u32*)(ws +  753664);             //   122,880
  u32* ggp  = (u32*)(ws +  876544);             //   122,880
  u32* rwp  = (u32*)(ws +  999424);             //    61,440
  f16* xpA  = (f16*)(ws + 1060864);             // 5,505,024
  f16* xpB  = (f16*)(ws + 6565888);             // 5,505,024
  f16* zstack = (f16*)(ws + 12070912);          // 74,711,040

  int S[NL+1]; S[NL] = 0;
  for (int i = NL-1; i >= 0; i--) S[i] = S[i+1] + (1 << (i % 10));

  prep3<<<dim3(484), 256, 0, stream>>>(sw, e1w, e2w, fw, gw, rw,
                                       wsk, e1f, e2f, fgp, ggp, rwp);

  f16* bufs[2] = {xpA, xpB};
  for (int tc0 = 0; tc0 < TF; tc0 += TC){
    int TcAct = TF - tc0; if (TcAct > TC) TcAct = TC;
    int cur = 0;
    for (int s = 0; s < 3; s++){
      int g0 = s*10;
      Trim7 tr;
      for (int li = 0; li < 7; li++) tr.t[li] = S[g0+li+1];
      int Lfinal = TcAct + S[g0+7];
      const f16* gin = (s == 0) ? (const f16*)nullptr : bufs[cur];
      const float* yArg = (s == 0) ? y : (const float*)nullptr;
      int nxt = (s == 0) ? 0 : (cur ^ 1);
      group7m<<<dim3((Lfinal + WGRP-1)/WGRP, NB), 256, 0, stream>>>(
          gin, yArg, cw, cb, tc0, bufs[nxt], zstack, g0, Lfinal, TcAct,
          fgp, ggp, rwp, tr);
      cur = nxt;
      for (int i = g0+7; i <= g0+9; i++){
        int d = 1 << (i % 10);
        int Tout = TcAct + S[i+1];
        singlem<<<dim3((Tout + 127)/128, NB), 256, 0, stream>>>(
            bufs[cur], bufs[cur^1], zstack + (size_t)i*ZLS,
            fgp + (size_t)i*1024, ggp + (size_t)i*1024, rwp + (size_t)i*512,
            Tout, d, S[i+1], TcAct);
        cur ^= 1;
      }
    }
    skipend<<<dim3((TcAct + 63)/64, NB), 256, 0, stream>>>(
        zstack, wsk, e1f, e1b, e2f, e2b, out, tc0, TcAct);
  }
}